// Round 6
// baseline (56.057 us; speedup 1.0000x reference)
//
#include <hip/hip_runtime.h>
#include <math.h>

typedef float vf4 __attribute__((ext_vector_type(4)));

__device__ __forceinline__ float wave_reduce_sum(float v) {
    #pragma unroll
    for (int off = 32; off > 0; off >>= 1)
        v += __shfl_xor(v, off, 64);
    return v;
}
__device__ __forceinline__ float wave_reduce_max(float v) {
    #pragma unroll
    for (int off = 32; off > 0; off >>= 1)
        v = fmaxf(v, __shfl_xor(v, off, 64));
    return v;
}

// fast tanh: tanh(x) = 1 - 2/(exp(2x)+1); exp via v_exp, recip via v_rcp
__device__ __forceinline__ float fast_tanh(float x) {
    float e = __expf(2.0f * x);
    return 1.0f - 2.0f * __builtin_amdgcn_rcpf(e + 1.0f);
}

// Kernel 1: rec[b*H + h] = dot(rnn_state[b,:], W_rec[h,:])
__global__ void rec_kernel(const float* __restrict__ rnn,
                           const float* __restrict__ Wrec,
                           float* __restrict__ rec,
                           int B, int H, int R) {
    int w    = (blockIdx.x * blockDim.x + threadIdx.x) >> 6;
    int lane = threadIdx.x & 63;
    int nOut = B * H;
    if (w >= nOut) return;
    int b = w / H;
    int h = w - b * H;
    const float* xr = rnn  + (size_t)b * R;
    const float* wr = Wrec + (size_t)h * R;
    float acc = 0.f;
    for (int r = lane * 4; r < R; r += 256) {
        vf4 a = *(const vf4*)(xr + r);
        vf4 c = *(const vf4*)(wr + r);
        acc += a.x * c.x + a.y * c.y + a.z * c.z + a.w * c.w;
    }
    acc = wave_reduce_sum(acc);
    if (lane == 0) rec[w] = acc;
}

// Kernel 2: each wave owns a fixed b and SCORE_ROWS consecutive t values.
// Per-row partials in acc[16]; one batched tree-reduce per strip; lanes 0..15
// do one coalesced 16-lane store into (B,T) scores.
#define SCORE_ROWS 16
__global__ void score_kernel(const float* __restrict__ enc,
                             const float* __restrict__ mask,
                             const float* __restrict__ rec,
                             const float* __restrict__ wsc,
                             const float* __restrict__ bsc,
                             float* __restrict__ scores_t,  // (B,T)
                             int T, int B, int H) {
    const int w    = (blockIdx.x * blockDim.x + threadIdx.x) >> 6;
    const int lane = threadIdx.x & 63;
    const int b     = w % B;
    const int tbase = (w / B) * SCORE_ROWS;
    if (tbase >= T) return;

    const int h0 = lane * 4;          // first half: h in [0, H/2)
    const int h1 = (H >> 1) + h0;     // second half

    const float* rr = rec + (size_t)b * H;
    vf4 r0 = *(const vf4*)(rr + h0);
    vf4 r1 = *(const vf4*)(rr + h1);
    vf4 w0 = *(const vf4*)(wsc + h0);
    vf4 w1 = *(const vf4*)(wsc + h1);
    const float bias = bsc[0];

    const float* erow = enc + ((size_t)tbase * B + b) * H;
    const size_t rstride = (size_t)B * H;

    float acc[SCORE_ROWS];
    #pragma unroll
    for (int i = 0; i < SCORE_ROWS; ++i) {
        const float* er = erow + (size_t)i * rstride;
        vf4 e0 = *(const vf4*)(er + h0);
        vf4 e1 = *(const vf4*)(er + h1);
        float a;
        a  = w0.x * fast_tanh(e0.x + r0.x);
        a += w0.y * fast_tanh(e0.y + r0.y);
        a += w0.z * fast_tanh(e0.z + r0.z);
        a += w0.w * fast_tanh(e0.w + r0.w);
        a += w1.x * fast_tanh(e1.x + r1.x);
        a += w1.y * fast_tanh(e1.y + r1.y);
        a += w1.z * fast_tanh(e1.z + r1.z);
        a += w1.w * fast_tanh(e1.w + r1.w);
        acc[i] = a;
    }

    // fold stages: 16 -> 8 -> 4 -> 2 -> 1 values across lane bits 0..3
    #pragma unroll
    for (int s = 0; s < 4; ++s) {
        const int bit = 1 << s;
        #pragma unroll
        for (int i = 0; i < (SCORE_ROWS >> (s + 1)); ++i) {
            float sent = (lane & bit) ? acc[2 * i]     : acc[2 * i + 1];
            float keep = (lane & bit) ? acc[2 * i + 1] : acc[2 * i];
            acc[i] = keep + __shfl_xor(sent, bit, 64);
        }
    }
    acc[0] += __shfl_xor(acc[0], 16, 64);
    acc[0] += __shfl_xor(acc[0], 32, 64);

    if (lane < SCORE_ROWS) {
        const int t = tbase + lane;
        scores_t[(size_t)b * T + t] = acc[0] + bias + mask[(size_t)t * B + b];
    }
}

// Kernel 3a: per-b softmax stats. One block per b; coalesced reads of the
// (B,T) score row; two passes (max, then exp-sum); writes {max, 1/sum}.
__global__ void stats_kernel(const float* __restrict__ scores_t,
                             float* __restrict__ stats, int T) {
    const int b    = blockIdx.x;
    const int tid  = threadIdx.x;
    const int wid  = tid >> 6;
    const int lane = tid & 63;
    const float* base = scores_t + (size_t)b * T;

    float m = -INFINITY;
    for (int i = tid * 4; i < T; i += 1024) {
        vf4 v = *(const vf4*)(base + i);
        m = fmaxf(m, fmaxf(fmaxf(v.x, v.y), fmaxf(v.z, v.w)));
    }
    m = wave_reduce_max(m);
    __shared__ float redm[4];
    if (lane == 0) redm[wid] = m;
    __syncthreads();
    m = fmaxf(fmaxf(redm[0], redm[1]), fmaxf(redm[2], redm[3]));

    float s = 0.f;
    for (int i = tid * 4; i < T; i += 1024) {
        vf4 v = *(const vf4*)(base + i);
        s += __expf(v.x - m) + __expf(v.y - m) + __expf(v.z - m) + __expf(v.w - m);
    }
    s = wave_reduce_sum(s);
    __shared__ float reds[4];
    if (lane == 0) reds[wid] = s;
    __syncthreads();
    if (tid == 0) {
        float ss = (reds[0] + reds[1]) + (reds[2] + reds[3]);
        stats[2 * b]     = m;
        stats[2 * b + 1] = 1.0f / ss;
    }
}

// Kernel 3b: finalize. Tile 64 t x 32 b: coalesced load from (B,T) scores,
// LDS transpose (padded, conflict-free), exp(x-m)*inv, coalesced store (T,B).
__global__ void finalize_kernel(const float* __restrict__ scores_t,
                                const float* __restrict__ stats,
                                float* __restrict__ out, int T, int B) {
    __shared__ float tile[32][65];
    __shared__ float sm[32];
    __shared__ float si[32];
    const int tid = threadIdx.x;
    const int t0  = blockIdx.x * 64;

    if (tid < B) {
        sm[tid] = stats[2 * tid];
        si[tid] = stats[2 * tid + 1];
    }
    __syncthreads();

    #pragma unroll
    for (int i = 0; i < 8; ++i) {
        int idx  = i * 256 + tid;
        int brow = idx >> 6;                 // 0..31
        int tcol = idx & 63;                 // 0..63
        tile[brow][tcol] = scores_t[(size_t)brow * T + t0 + tcol];
    }
    __syncthreads();

    #pragma unroll
    for (int i = 0; i < 8; ++i) {
        int idx  = i * 256 + tid;
        int trow = idx >> 5;                 // 0..63
        int bcol = idx & 31;                 // 0..31
        float x = tile[bcol][trow];
        float r = __expf(x - sm[bcol]) * si[bcol];
        out[(size_t)(t0 + trow) * B + bcol] = r;
    }
}

extern "C" void kernel_launch(void* const* d_in, const int* in_sizes, int n_in,
                              void* d_out, int out_size, void* d_ws, size_t ws_size,
                              hipStream_t stream) {
    const float* enc  = (const float*)d_in[0];  // (T,B,H)
    const float* mask = (const float*)d_in[1];  // (T,B)
    const float* rnn  = (const float*)d_in[2];  // (B,R)
    // d_in[3] = prev_att_weights, unused by the reference
    const float* Wrec = (const float*)d_in[4];  // (H,R)
    const float* wsc  = (const float*)d_in[5];  // (H,)
    const float* bsc  = (const float*)d_in[6];  // (1,)

    const int H = in_sizes[5];
    const int R = in_sizes[4] / H;
    const int B = in_sizes[2] / R;
    const int T = in_sizes[1] / B;

    float* rec      = (float*)d_ws;                       // B*H floats
    float* scores_t = rec + (size_t)B * H;                // (B,T) floats
    float* stats    = scores_t + (size_t)B * T;           // 2*B floats
    float* out      = (float*)d_out;                      // (T,B)

    // Kernel 1: B*H outputs, one wave each
    {
        int nOut   = B * H;
        int blocks = (nOut + 3) / 4;
        rec_kernel<<<blocks, 256, 0, stream>>>(rnn, Wrec, rec, B, H, R);
    }
    // Kernel 2: one wave per (b, 16-row strip)
    {
        int nWaves = (T / SCORE_ROWS) * B;
        int blocks = (nWaves + 3) / 4;
        score_kernel<<<blocks, 256, 0, stream>>>(enc, mask, rec, wsc, bsc,
                                                 scores_t, T, B, H);
    }
    // Kernel 3a: one block per b
    stats_kernel<<<B, 1024, 0, stream>>>(scores_t, stats, T);
    // Kernel 3b: one block per 64-t tile
    finalize_kernel<<<T / 64, 256, 0, stream>>>(scores_t, stats, out, T, B);
}